// Round 13
// baseline (529.161 us; speedup 1.0000x reference)
//
#include <hip/hip_runtime.h>
#include <cstdint>

#define NTOK 49
#define CDIM 512
#define BW 2048
#define MROWS (BW * NTOK)   // 100352
#define QKVN 1536

typedef __attribute__((ext_vector_type(4))) float f32x4;
typedef __attribute__((ext_vector_type(8))) short s16x8;
typedef __attribute__((ext_vector_type(4))) unsigned int u32x4;
typedef __attribute__((ext_vector_type(2))) unsigned int u32x2;

__device__ __forceinline__ uint16_t f2b(float f) {
  uint32_t u = __float_as_uint(f);
  u += 0x7fffu + ((u >> 16) & 1u);
  return (uint16_t)(u >> 16);
}
__device__ __forceinline__ float b2f(uint16_t h) {
  return __uint_as_float(((uint32_t)h) << 16);
}
__device__ __forceinline__ unsigned cvtpk(float lo, float hi) {
  unsigned r;
  asm("v_cvt_pk_bf16_f32 %0, %1, %2" : "=v"(r) : "v"(lo), "v"(hi));
  return r;
}

#define GLOAD_LDS16(gp, lp)                                                    \
  __builtin_amdgcn_global_load_lds(                                            \
      (__attribute__((address_space(1))) void*)(gp),                           \
      (__attribute__((address_space(3))) void*)(lp), 16, 0, 0)

// --- merged prep: x->bf16 | weights | T-table (rpe MLP computed in-block) ---
__global__ __launch_bounds__(256) void prep_all(
    const float* __restrict__ x, uint16_t* __restrict__ xb,
    const float* __restrict__ qkv_w, const float* __restrict__ proj_w,
    const float* __restrict__ q_bias, const float* __restrict__ v_bias,
    uint16_t* __restrict__ qkv_wT, uint16_t* __restrict__ proj_wT,
    float* __restrict__ qkv_bias, const float* __restrict__ w1,
    const float* __restrict__ b1, const float* __restrict__ w2,
    const float* __restrict__ mask, uint16_t* __restrict__ Tt) {
  const int bid = blockIdx.x;
  if (bid < 50176) {
    long i = ((long)bid * 256 + threadIdx.x) * 4;
    f32x4 v = *(const f32x4*)(x + i);
    uint64_t p = (uint64_t)f2b(v[0]) | ((uint64_t)f2b(v[1]) << 16) |
                 ((uint64_t)f2b(v[2]) << 32) | ((uint64_t)f2b(v[3]) << 48);
    *(uint64_t*)(xb + i) = p;
  } else if (bid < 50176 + 3072) {
    int i = (bid - 50176) * 256 + threadIdx.x;
    if (i < QKVN * CDIM) {
      int nn = i / CDIM, kk = i % CDIM;
      qkv_wT[i] = f2b(qkv_w[(long)kk * QKVN + nn]);
    }
    if (i < CDIM * CDIM) {
      int nn = i / CDIM, kk = i % CDIM;
      proj_wT[i] = f2b(proj_w[(long)kk * CDIM + nn]);
    }
    if (i < QKVN) {
      float bv = (i < 512) ? q_bias[i] : (i < 1024 ? 0.f : v_bias[i - 1024]);
      qkv_bias[i] = bv;
    }
  } else {
    // T-table block per (w,h): compute the 169 rpe-MLP biases in LDS, then
    // T = exp(mask + 16*sigmoid(pb)) in MFMA C-layout.
    __shared__ float bias_h[176];
    const int idx = bid - 53248;          // 0..1023
    const int w = idx >> 4, h = idx & 15;
    if (threadIdx.x < 169) {
      int f = threadIdx.x;
      float d0 = (float)((f % 13) - 6);
      float d1 = (float)((f / 13) - 6);
      const float inv_log8 = 0.4808983469629878f;  // 1/ln(8)
      float v0 = (d0 / 11.0f) * (8.0f / 11.0f);
      float v1 = (d1 / 11.0f) * (8.0f / 11.0f);
      float f0 = copysignf(log1pf(fabsf(v0)) * inv_log8, v0);
      if (v0 == 0.f) f0 = 0.f;
      float f1 = copysignf(log1pf(fabsf(v1)) * inv_log8, v1);
      if (v1 == 0.f) f1 = 0.f;
      float acc = 0.f;
      for (int k = 0; k < 512; ++k) {   // weights thread-uniform -> s_loads
        float h1 = fmaxf(f0 * w1[k] + f1 * w1[512 + k] + b1[k], 0.f);
        acc += h1 * w2[k * 16 + h];
      }
      bias_h[f] = 16.f / (1.f + expf(-acc));
    }
    __syncthreads();
    const int nt = threadIdx.x >> 6, lane = threadIdx.x & 63;
    const int cc = lane & 15, gg = lane >> 4;
    const int q = nt * 16 + cc;
    uint16_t out[16];
#pragma unroll
    for (int mt = 0; mt < 4; ++mt)
#pragma unroll
      for (int j = 0; j < 4; ++j) {
        int k = mt * 16 + gg * 4 + j;
        float T;
        if (k >= 49) T = 0.f;
        else if (q >= 49) T = 1.f;
        else {
          int ridx = (q % 7 - k % 7 + 6) * 13 + (q / 7 - k / 7 + 6);
          T = __expf(mask[(long)w * 2401 + q * 49 + k] + bias_h[ridx]);
        }
        out[mt * 4 + j] = f2b(T);
      }
    uint16_t* dst = Tt + ((long)(w * 16 + h) * 4096 + nt * 1024 + lane * 16);
#pragma unroll
    for (int p = 0; p < 2; ++p)
      *(u32x4*)(dst + p * 8) = *(const u32x4*)(out + p * 8);
  }
}

// ============ 256x256 8-phase GEMM (round-4 proven form, FROZEN) ==========

#define STAGE_A(tile, half, buf)                                               \
  {                                                                            \
    const uint16_t* s_ = srcA + (half) * (128L * 512) + (long)(tile) * 64;     \
    uint16_t* d_ = &lds[(buf) * 32768 + (half) * 8192 + tid * 8];              \
    GLOAD_LDS16(s_, d_);                                                       \
    GLOAD_LDS16(s_ + 64 * 512, d_ + 4096);                                     \
  }

#define STAGE_B(tile, half, buf)                                               \
  {                                                                            \
    const uint16_t* s_ = srcB + (half) * (128L * 512) + (long)(tile) * 64;     \
    uint16_t* d_ = &lds[(buf) * 32768 + 16384 + (half) * 8192 + tid * 8];      \
    GLOAD_LDS16(s_, d_);                                                       \
    GLOAD_LDS16(s_ + 64 * 512, d_ + 4096);                                     \
  }

#define VM4 asm volatile("s_waitcnt vmcnt(4)" ::: "memory");
#define VM0 asm volatile("s_waitcnt vmcnt(0)" ::: "memory");

#define PHASE(buf, q, STAGES, TAIL)                                            \
  {                                                                            \
    s16x8 a00 = *(const s16x8*)&lds[(buf)*32768 + arow + (2*(q))*1024 + ax0];  \
    s16x8 a01 = *(const s16x8*)&lds[(buf)*32768 + arow + (2*(q))*1024 + ax1];  \
    s16x8 a10 = *(const s16x8*)&lds[(buf)*32768 + arow + (2*(q)+1)*1024 + ax0];\
    s16x8 a11 = *(const s16x8*)&lds[(buf)*32768 + arow + (2*(q)+1)*1024 + ax1];\
    if ((q) == 0) {                                                            \
      _Pragma("unroll")                                                        \
      for (int nf = 0; nf < 4; ++nf) {                                         \
        bfr0[nf] = *(const s16x8*)&lds[(buf)*32768 + brow_ + nf*1024 + ax0];   \
        bfr1[nf] = *(const s16x8*)&lds[(buf)*32768 + brow_ + nf*1024 + ax1];   \
      }                                                                        \
    }                                                                          \
    STAGES                                                                     \
    __builtin_amdgcn_s_barrier();                                              \
    asm volatile("s_waitcnt lgkmcnt(0)" ::: "memory");                         \
    __builtin_amdgcn_sched_barrier(0);                                         \
    __builtin_amdgcn_s_setprio(1);                                             \
    _Pragma("unroll")                                                          \
    for (int nf = 0; nf < 4; ++nf) {                                           \
      acc[2*(q)][nf] = __builtin_amdgcn_mfma_f32_16x16x32_bf16(                \
          a00, bfr0[nf], acc[2*(q)][nf], 0, 0, 0);                             \
      acc[2*(q)][nf] = __builtin_amdgcn_mfma_f32_16x16x32_bf16(                \
          a01, bfr1[nf], acc[2*(q)][nf], 0, 0, 0);                             \
      acc[2*(q)+1][nf] = __builtin_amdgcn_mfma_f32_16x16x32_bf16(              \
          a10, bfr0[nf], acc[2*(q)+1][nf], 0, 0, 0);                           \
      acc[2*(q)+1][nf] = __builtin_amdgcn_mfma_f32_16x16x32_bf16(              \
          a11, bfr1[nf], acc[2*(q)+1][nf], 0, 0, 0);                           \
    }                                                                          \
    __builtin_amdgcn_s_setprio(0);                                             \
    TAIL                                                                       \
    __builtin_amdgcn_s_barrier();                                              \
  }

template <int EPI>  // 0: bf16 out, 1: f32 out
__global__ __launch_bounds__(512, 2) void gemm8p(const uint16_t* __restrict__ A,
                                                 const uint16_t* __restrict__ BT,
                                                 const float* __restrict__ bias,
                                                 void* __restrict__ Cout,
                                                 int N, int ntn) {
  __shared__ uint16_t lds[2 * 32768];  // 131072 B
  const int tid = threadIdx.x;
  const int wave = tid >> 6, lane = tid & 63;
  const int wm = wave >> 2, wn = wave & 3;  // 2 x 4 waves
  const int c = lane & 15, g = lane >> 4;

  const int bid = blockIdx.x;
  const int nwg = gridDim.x;
  const int wg = (bid & 7) * (nwg >> 3) + (bid >> 3);  // XCD swizzle (nwg%8==0)
  const int mt = wg / ntn, nt = wg % ntn;
  const long brow = (long)mt * 256;
  const int bcol = nt * 256;

  const int lr0 = tid >> 3;
  const int chunk = tid & 7;
  const int scol = (chunk ^ (lr0 & 7)) * 8;
  const uint16_t* srcA = A + (brow + lr0) * 512 + scol;
  const uint16_t* srcB = BT + ((long)bcol + lr0) * 512 + scol;

  const int arow = wm * 8192 + c * 64;
  const int brow_ = 16384 + (wn >> 1) * 8192 + ((wn & 1) * 64 + c) * 64;
  const int ax0 = (g * 8) ^ ((c & 7) * 8);
  const int ax1 = (32 + g * 8) ^ ((c & 7) * 8);

  f32x4 acc[8][4];
#pragma unroll
  for (int i = 0; i < 8; ++i)
#pragma unroll
    for (int j = 0; j < 4; ++j) acc[i][j] = f32x4{0.f, 0.f, 0.f, 0.f};
  s16x8 bfr0[4], bfr1[4];

  STAGE_A(0, 0, 0); STAGE_A(0, 1, 0);
  STAGE_B(0, 0, 0); STAGE_B(0, 1, 0);
  STAGE_B(1, 0, 1); STAGE_B(1, 1, 1);
  VM4
  __builtin_amdgcn_s_barrier();

  for (int i = 0; i < 3; ++i) {
    const int t0 = 2 * i;
    PHASE(0, 0, STAGE_A(t0 + 1, 0, 1), )
    PHASE(0, 1, STAGE_A(t0 + 1, 1, 1), )
    PHASE(0, 2, STAGE_B(t0 + 2, 0, 0), )
    PHASE(0, 3, STAGE_B(t0 + 2, 1, 0), VM4)
    PHASE(1, 0, STAGE_A(t0 + 2, 0, 0), )
    PHASE(1, 1, STAGE_A(t0 + 2, 1, 0), )
    PHASE(1, 2, STAGE_B(t0 + 3, 0, 1), )
    PHASE(1, 3, STAGE_B(t0 + 3, 1, 1), VM4)
  }
  PHASE(0, 0, STAGE_A(7, 0, 1), )
  PHASE(0, 1, STAGE_A(7, 1, 1), )
  PHASE(0, 2, , )
  PHASE(0, 3, , VM0)
  PHASE(1, 0, , )
  PHASE(1, 1, , )
  PHASE(1, 2, , )
  PHASE(1, 3, , )

#pragma unroll
  for (int mf = 0; mf < 8; ++mf) {
#pragma unroll
    for (int nf = 0; nf < 4; ++nf) {
      const int col = bcol + wn * 64 + nf * 16 + c;
      const float bv = bias[col];
#pragma unroll
      for (int r = 0; r < 4; ++r) {
        const long grow = brow + wm * 128 + mf * 16 + g * 4 + r;
        const float v = acc[mf][nf][r] + bv;
        if (EPI == 0)
          ((uint16_t*)Cout)[grow * N + col] = f2b(v);
        else
          ((float*)Cout)[grow * N + col] = v;
      }
    }
  }
}

// ------- MFMA attention (r9 single-window form, cvtpk packing) -------
__global__ __launch_bounds__(256, 4) void attn_mfma(
    const uint16_t* __restrict__ qkv,   // [100352][1536] bf16 (q|k|v)
    const float* __restrict__ logit_scale,
    const uint16_t* __restrict__ Tt,    // [w][h][nt][lane][mt][4] bf16
    uint16_t* __restrict__ outb) {      // [100352][512] bf16
  __shared__ uint16_t Vs[4][2048];
  const int tid = threadIdx.x;
  const int wave = tid >> 6, lane = tid & 63;
  const int g = lane >> 4, c = lane & 15;
  const int b = blockIdx.x >> 2;
  const int h = ((blockIdx.x & 3) << 2) | wave;
  const long rbase = (long)b * 49;

  uint16_t* vdst = Vs[wave];
#pragma unroll
  for (int i = 0; i < 4; ++i) {
    int chunk = i * 64 + lane;
    int row = chunk >> 2, part = chunk & 3;
    if (row > 48) { row = 0; part = 0; }
    GLOAD_LDS16(qkv + (rbase + row) * QKVN + 1024 + h * 32 + part * 8,
                vdst + i * 512 + lane * 8);
  }

  const long qoff = rbase * QKVN + h * 32;
  s16x8 kf[4], qf[4];
#pragma unroll
  for (int t = 0; t < 4; ++t) {
    int row = t * 16 + c;
    s16x8 kv = {}, qv = {};
    if (row < 49) {
      qv = *(const s16x8*)(qkv + qoff + (long)row * QKVN + g * 8);
      kv = *(const s16x8*)(qkv + qoff + (long)row * QKVN + 512 + g * 8);
    }
    float kfv[8], qfv[8];
    float kss = 0.f, qss = 0.f;
#pragma unroll
    for (int m = 0; m < 8; ++m) {
      kfv[m] = b2f((uint16_t)kv[m]); kss += kfv[m] * kfv[m];
      qfv[m] = b2f((uint16_t)qv[m]); qss += qfv[m] * qfv[m];
    }
    kss += __shfl_xor(kss, 16); kss += __shfl_xor(kss, 32);
    qss += __shfl_xor(qss, 16); qss += __shfl_xor(qss, 32);
    float kr = rsqrtf(fmaxf(kss, 1e-12f));
    float qr = rsqrtf(fmaxf(qss, 1e-12f));
#pragma unroll
    for (int m = 0; m < 8; ++m) {
      kv[m] = (short)f2b(kfv[m] * kr);
      qv[m] = (short)f2b(qfv[m] * qr);
    }
    kf[t] = kv; qf[t] = qv;
  }

  const float scale = __expf(fminf(logit_scale[h], 4.6051702f));
  const uint16_t* Tbase = Tt + (long)(((b & 63) * 16 + h)) * 4096;

  u32x4 aT[4][2];
  const int dstlo = (c + 16 * (g >> 1)) * 4;
  const int dsthi = (c + 16 * (2 + (g >> 1))) * 4;
  const bool godd = (g & 1) != 0;
  const bool low = (lane < 32);

#pragma unroll
  for (int nt = 0; nt < 4; ++nt) {
    s16x8 t01 = *(const s16x8*)(Tbase + nt * 1024 + lane * 16);
    s16x8 t23 = *(const s16x8*)(Tbase + nt * 1024 + lane * 16 + 8);

    f32x4 sv[4];
    __builtin_amdgcn_s_setprio(1);
#pragma unroll
    for (int mt = 0; mt < 4; ++mt)
      sv[mt] = __builtin_amdgcn_mfma_f32_16x16x32_bf16(
          kf[mt], qf[nt], f32x4{0.f, 0.f, 0.f, 0.f}, 0, 0, 0);
    __builtin_amdgcn_s_setprio(0);

    float mx = -3.0e38f;
#pragma unroll
    for (int mt = 0; mt < 4; ++mt)
#pragma unroll
      for (int j = 0; j < 4; ++j) {
        sv[mt][j] *= scale;
        mx = fmaxf(mx, sv[mt][j]);
      }
    mx = fmaxf(mx, __shfl_xor(mx, 16));
    mx = fmaxf(mx, __shfl_xor(mx, 32));
    float sum = 0.f;
#pragma unroll
    for (int mt = 0; mt < 4; ++mt) {
#pragma unroll
      for (int j = 0; j < 4; ++j) {
        uint16_t tb = (uint16_t)((mt < 2) ? t01[mt * 4 + j] : t23[(mt - 2) * 4 + j]);
        float e = b2f(tb) * __expf(sv[mt][j] - mx);
        sv[mt][j] = e; sum += e;
      }
    }
    sum += __shfl_xor(sum, 16);
    sum += __shfl_xor(sum, 32);
    float inv = 1.0f / sum;
#pragma unroll
    for (int mt = 0; mt < 4; ++mt)
#pragma unroll
      for (int j = 0; j < 4; ++j) sv[mt][j] *= inv;

    unsigned pk[4][2];
#pragma unroll
    for (int mt = 0; mt < 4; ++mt) {
      pk[mt][0] = cvtpk(sv[mt][0], sv[mt][1]);
      pk[mt][1] = cvtpk(sv[mt][2], sv[mt][3]);
    }
#pragma unroll
    for (int x = 0; x < 2; ++x)
#pragma unroll
      for (int K = 0; K < 2; ++K) {
        int vA = godd ? (int)pk[2 * K + 1][x] : (int)pk[2 * K][x];
        int dA = godd ? dsthi : dstlo;
        int rA = __builtin_amdgcn_ds_permute(dA, vA);
        int vB = godd ? (int)pk[2 * K][x] : (int)pk[2 * K + 1][x];
        int dB = godd ? dstlo : dsthi;
        int rB = __builtin_amdgcn_ds_permute(dB, vB);
        aT[nt][K][x]     = (unsigned)(low ? rA : rB);
        aT[nt][K][2 + x] = (unsigned)(low ? rB : rA);
      }
  }

  asm volatile("s_waitcnt vmcnt(0)" ::: "memory");

  f32x4 o[4][2];
#pragma unroll
  for (int qt = 0; qt < 4; ++qt)
#pragma unroll
    for (int dt = 0; dt < 2; ++dt) o[qt][dt] = f32x4{0.f, 0.f, 0.f, 0.f};

#pragma unroll
  for (int ks = 0; ks < 2; ++ks) {
    s16x8 vf[2];
#pragma unroll
    for (int dt = 0; dt < 2; ++dt) {
      int d = dt * 16 + c;
      s16x8 vv;
#pragma unroll
      for (int jj = 0; jj < 8; ++jj) {
        int k = ks * 32 + g * 8 + jj;
        vv[jj] = (short)vdst[k * 32 + d];
      }
      vf[dt] = vv;
    }
    __builtin_amdgcn_s_setprio(1);
#pragma unroll
    for (int qt = 0; qt < 4; ++qt) {
      s16x8 pf = __builtin_bit_cast(s16x8, aT[qt][ks]);
#pragma unroll
      for (int dt = 0; dt < 2; ++dt)
        o[qt][dt] = __builtin_amdgcn_mfma_f32_16x16x32_bf16(pf, vf[dt],
                                                            o[qt][dt], 0, 0, 0);
    }
    __builtin_amdgcn_s_setprio(0);
  }

#pragma unroll
  for (int qt = 0; qt < 4; ++qt) {
    int q0 = qt * 16 + g * 4;
#pragma unroll
    for (int dt = 0; dt < 2; ++dt)
#pragma unroll
      for (int j = 0; j < 4; ++j) {
        int q = q0 + j;
        if (q < 49) vdst[q * 40 + dt * 16 + c] = f2b(o[qt][dt][j]);
      }
  }
#pragma unroll
  for (int i = 0; i < 4; ++i) {
    int row = i * 16 + (lane >> 2);
    if (row < 49) {
      int chunk = lane & 3;
      s16x8 ov = *(const s16x8*)&vdst[row * 40 + chunk * 8];
      *(s16x8*)(outb + (rbase + row) * 512 + h * 32 + chunk * 8) = ov;
    }
  }
}

extern "C" void kernel_launch(void* const* d_in, const int* in_sizes, int n_in,
                              void* d_out, int out_size, void* d_ws,
                              size_t ws_size, hipStream_t stream) {
  const float* x = (const float*)d_in[0];
  const float* mask = (const float*)d_in[1];
  const float* qkv_w = (const float*)d_in[2];
  const float* q_bias = (const float*)d_in[3];
  const float* v_bias = (const float*)d_in[4];
  const float* logit_scale = (const float*)d_in[5];
  const float* rpe_w1 = (const float*)d_in[6];
  const float* rpe_b1 = (const float*)d_in[7];
  const float* rpe_w2 = (const float*)d_in[8];
  const float* proj_w = (const float*)d_in[9];
  const float* proj_b = (const float*)d_in[10];

  char* ws = (char*)d_ws;
  uint16_t* xb       = (uint16_t*)ws;                   // x bf16; later attn out
  uint16_t* qkvbuf   = (uint16_t*)(ws + 102760448L);    // [100352][1536]
  uint16_t* qkv_wT   = (uint16_t*)(ws + 411041792L);
  uint16_t* proj_wT  = (uint16_t*)(ws + 412614656L);
  float*    qkv_bias = (float*)(ws + 413138944L);
  uint16_t* Tt       = (uint16_t*)(ws + 413147136L);    // 8,388,608 B

  prep_all<<<54272, 256, 0, stream>>>(x, xb, qkv_w, proj_w, q_bias, v_bias,
                                      qkv_wT, proj_wT, qkv_bias, rpe_w1,
                                      rpe_b1, rpe_w2, mask, Tt);

  gemm8p<0><<<2352, 512, 0, stream>>>(xb, qkv_wT, qkv_bias, qkvbuf, QKVN, 6);
  attn_mfma<<<8192, 256, 0, stream>>>(qkvbuf, logit_scale, Tt, xb);
  gemm8p<1><<<784, 512, 0, stream>>>(xb, proj_wT, proj_b, d_out, CDIM, 2);
}

// Round 14
// 500.453 us; speedup vs baseline: 1.0574x; 1.0574x over previous
//
#include <hip/hip_runtime.h>
#include <cstdint>

#define NTOK 49
#define CDIM 512
#define BW 2048
#define MROWS (BW * NTOK)   // 100352
#define QKVN 1536

typedef __attribute__((ext_vector_type(4))) float f32x4;
typedef __attribute__((ext_vector_type(8))) short s16x8;
typedef __attribute__((ext_vector_type(4))) unsigned int u32x4;
typedef __attribute__((ext_vector_type(2))) unsigned int u32x2;

__device__ __forceinline__ uint16_t f2b(float f) {
  uint32_t u = __float_as_uint(f);
  u += 0x7fffu + ((u >> 16) & 1u);
  return (uint16_t)(u >> 16);
}
__device__ __forceinline__ float b2f(uint16_t h) {
  return __uint_as_float(((uint32_t)h) << 16);
}

#define GLOAD_LDS16(gp, lp)                                                    \
  __builtin_amdgcn_global_load_lds(                                            \
      (__attribute__((address_space(1))) void*)(gp),                           \
      (__attribute__((address_space(3))) void*)(lp), 16, 0, 0)

// ------- merged prep: x->bf16 | weight transpose+bf16 | rpe MLP table -------
__global__ __launch_bounds__(256) void prep_all(
    const float* __restrict__ x, uint16_t* __restrict__ xb,
    const float* __restrict__ qkv_w, const float* __restrict__ proj_w,
    const float* __restrict__ q_bias, const float* __restrict__ v_bias,
    uint16_t* __restrict__ qkv_wT, uint16_t* __restrict__ proj_wT,
    float* __restrict__ qkv_bias, const float* __restrict__ w1,
    const float* __restrict__ b1, const float* __restrict__ w2,
    float* __restrict__ bias16) {
  const int bid = blockIdx.x;
  if (bid < 50176) {
    long i = ((long)bid * 256 + threadIdx.x) * 4;
    f32x4 v = *(const f32x4*)(x + i);
    uint64_t p = (uint64_t)f2b(v[0]) | ((uint64_t)f2b(v[1]) << 16) |
                 ((uint64_t)f2b(v[2]) << 32) | ((uint64_t)f2b(v[3]) << 48);
    *(uint64_t*)(xb + i) = p;
  } else if (bid < 50176 + 3072) {
    int i = (bid - 50176) * 256 + threadIdx.x;
    if (i < QKVN * CDIM) {
      int nn = i / CDIM, kk = i % CDIM;
      qkv_wT[i] = f2b(qkv_w[(long)kk * QKVN + nn]);
    }
    if (i < CDIM * CDIM) {
      int nn = i / CDIM, kk = i % CDIM;
      proj_wT[i] = f2b(proj_w[(long)kk * CDIM + nn]);
    }
    if (i < QKVN) {
      float bv = (i < 512) ? q_bias[i] : (i < 1024 ? 0.f : v_bias[i - 1024]);
      qkv_bias[i] = bv;
    }
  } else {
    int i = (bid - 53248) * 256 + threadIdx.x;
    if (i >= 169 * 16) return;
    int f = i >> 4, h = i & 15;
    float d0 = (float)((f % 13) - 6);
    float d1 = (float)((f / 13) - 6);
    const float inv_log8 = 0.4808983469629878f;  // 1/ln(8)
    float v0 = (d0 / 11.0f) * (8.0f / 11.0f);
    float v1 = (d1 / 11.0f) * (8.0f / 11.0f);
    float f0 = copysignf(log1pf(fabsf(v0)) * inv_log8, v0);
    if (v0 == 0.f) f0 = 0.f;
    float f1 = copysignf(log1pf(fabsf(v1)) * inv_log8, v1);
    if (v1 == 0.f) f1 = 0.f;
    float acc = 0.f;
    for (int k = 0; k < 512; ++k) {
      float h1 = fmaxf(f0 * w1[k] + f1 * w1[512 + k] + b1[k], 0.f);
      acc += h1 * w2[k * 16 + h];
    }
    bias16[i] = 16.f / (1.f + expf(-acc));
  }
}

// ---- multiplicative table T = exp(mask + 16*sigmoid(pb)), bf16 ----
__global__ __launch_bounds__(256) void build_T(const float* __restrict__ mask,
                                               const float* __restrict__ bias16,
                                               uint16_t* __restrict__ Tt) {
  const int w = blockIdx.x >> 4, h = blockIdx.x & 15;
  const int nt = threadIdx.x >> 6, lane = threadIdx.x & 63;
  const int cc = lane & 15, gg = lane >> 4;
  const int q = nt * 16 + cc;
  uint16_t out[16];
#pragma unroll
  for (int mt = 0; mt < 4; ++mt)
#pragma unroll
    for (int j = 0; j < 4; ++j) {
      int k = mt * 16 + gg * 4 + j;
      float T;
      if (k >= 49) T = 0.f;
      else if (q >= 49) T = 1.f;
      else {
        int ridx = (q % 7 - k % 7 + 6) * 13 + (q / 7 - k / 7 + 6);
        T = __expf(mask[(long)w * 2401 + q * 49 + k] + bias16[ridx * 16 + h]);
      }
      out[mt * 4 + j] = f2b(T);
    }
  uint16_t* dst = Tt + ((long)(w * 16 + h) * 4096 + nt * 1024 + lane * 16);
#pragma unroll
  for (int p = 0; p < 2; ++p)
    *(u32x4*)(dst + p * 8) = *(const u32x4*)(out + p * 8);
}

// ============ 256x256 8-phase GEMM (round-4 proven form, FROZEN) ==========

#define STAGE_A(tile, half, buf)                                               \
  {                                                                            \
    const uint16_t* s_ = srcA + (half) * (128L * 512) + (long)(tile) * 64;     \
    uint16_t* d_ = &lds[(buf) * 32768 + (half) * 8192 + tid * 8];              \
    GLOAD_LDS16(s_, d_);                                                       \
    GLOAD_LDS16(s_ + 64 * 512, d_ + 4096);                                     \
  }

#define STAGE_B(tile, half, buf)                                               \
  {                                                                            \
    const uint16_t* s_ = srcB + (half) * (128L * 512) + (long)(tile) * 64;     \
    uint16_t* d_ = &lds[(buf) * 32768 + 16384 + (half) * 8192 + tid * 8];      \
    GLOAD_LDS16(s_, d_);                                                       \
    GLOAD_LDS16(s_ + 64 * 512, d_ + 4096);                                     \
  }

#define VM4 asm volatile("s_waitcnt vmcnt(4)" ::: "memory");
#define VM0 asm volatile("s_waitcnt vmcnt(0)" ::: "memory");

#define PHASE(buf, q, STAGES, TAIL)                                            \
  {                                                                            \
    s16x8 a00 = *(const s16x8*)&lds[(buf)*32768 + arow + (2*(q))*1024 + ax0];  \
    s16x8 a01 = *(const s16x8*)&lds[(buf)*32768 + arow + (2*(q))*1024 + ax1];  \
    s16x8 a10 = *(const s16x8*)&lds[(buf)*32768 + arow + (2*(q)+1)*1024 + ax0];\
    s16x8 a11 = *(const s16x8*)&lds[(buf)*32768 + arow + (2*(q)+1)*1024 + ax1];\
    if ((q) == 0) {                                                            \
      _Pragma("unroll")                                                        \
      for (int nf = 0; nf < 4; ++nf) {                                         \
        bfr0[nf] = *(const s16x8*)&lds[(buf)*32768 + brow_ + nf*1024 + ax0];   \
        bfr1[nf] = *(const s16x8*)&lds[(buf)*32768 + brow_ + nf*1024 + ax1];   \
      }                                                                        \
    }                                                                          \
    STAGES                                                                     \
    __builtin_amdgcn_s_barrier();                                              \
    asm volatile("s_waitcnt lgkmcnt(0)" ::: "memory");                         \
    __builtin_amdgcn_sched_barrier(0);                                         \
    __builtin_amdgcn_s_setprio(1);                                             \
    _Pragma("unroll")                                                          \
    for (int nf = 0; nf < 4; ++nf) {                                           \
      acc[2*(q)][nf] = __builtin_amdgcn_mfma_f32_16x16x32_bf16(                \
          a00, bfr0[nf], acc[2*(q)][nf], 0, 0, 0);                             \
      acc[2*(q)][nf] = __builtin_amdgcn_mfma_f32_16x16x32_bf16(                \
          a01, bfr1[nf], acc[2*(q)][nf], 0, 0, 0);                             \
      acc[2*(q)+1][nf] = __builtin_amdgcn_mfma_f32_16x16x32_bf16(              \
          a10, bfr0[nf], acc[2*(q)+1][nf], 0, 0, 0);                           \
      acc[2*(q)+1][nf] = __builtin_amdgcn_mfma_f32_16x16x32_bf16(              \
          a11, bfr1[nf], acc[2*(q)+1][nf], 0, 0, 0);                           \
    }                                                                          \
    __builtin_amdgcn_s_setprio(0);                                             \
    TAIL                                                                       \
    __builtin_amdgcn_s_barrier();                                              \
  }

template <int EPI>  // 0: bf16 out, 1: f32 out
__global__ __launch_bounds__(512, 2) void gemm8p(const uint16_t* __restrict__ A,
                                                 const uint16_t* __restrict__ BT,
                                                 const float* __restrict__ bias,
                                                 void* __restrict__ Cout,
                                                 int N, int ntn) {
  __shared__ uint16_t lds[2 * 32768];  // 131072 B
  const int tid = threadIdx.x;
  const int wave = tid >> 6, lane = tid & 63;
  const int wm = wave >> 2, wn = wave & 3;  // 2 x 4 waves
  const int c = lane & 15, g = lane >> 4;

  const int bid = blockIdx.x;
  const int nwg = gridDim.x;
  const int wg = (bid & 7) * (nwg >> 3) + (bid >> 3);  // XCD swizzle (nwg%8==0)
  const int mt = wg / ntn, nt = wg % ntn;
  const long brow = (long)mt * 256;
  const int bcol = nt * 256;

  const int lr0 = tid >> 3;
  const int chunk = tid & 7;
  const int scol = (chunk ^ (lr0 & 7)) * 8;
  const uint16_t* srcA = A + (brow + lr0) * 512 + scol;
  const uint16_t* srcB = BT + ((long)bcol + lr0) * 512 + scol;

  const int arow = wm * 8192 + c * 64;
  const int brow_ = 16384 + (wn >> 1) * 8192 + ((wn & 1) * 64 + c) * 64;
  const int ax0 = (g * 8) ^ ((c & 7) * 8);
  const int ax1 = (32 + g * 8) ^ ((c & 7) * 8);

  f32x4 acc[8][4];
#pragma unroll
  for (int i = 0; i < 8; ++i)
#pragma unroll
    for (int j = 0; j < 4; ++j) acc[i][j] = f32x4{0.f, 0.f, 0.f, 0.f};
  s16x8 bfr0[4], bfr1[4];

  STAGE_A(0, 0, 0); STAGE_A(0, 1, 0);
  STAGE_B(0, 0, 0); STAGE_B(0, 1, 0);
  STAGE_B(1, 0, 1); STAGE_B(1, 1, 1);
  VM4
  __builtin_amdgcn_s_barrier();

  for (int i = 0; i < 3; ++i) {
    const int t0 = 2 * i;
    PHASE(0, 0, STAGE_A(t0 + 1, 0, 1), )
    PHASE(0, 1, STAGE_A(t0 + 1, 1, 1), )
    PHASE(0, 2, STAGE_B(t0 + 2, 0, 0), )
    PHASE(0, 3, STAGE_B(t0 + 2, 1, 0), VM4)
    PHASE(1, 0, STAGE_A(t0 + 2, 0, 0), )
    PHASE(1, 1, STAGE_A(t0 + 2, 1, 0), )
    PHASE(1, 2, STAGE_B(t0 + 3, 0, 1), )
    PHASE(1, 3, STAGE_B(t0 + 3, 1, 1), VM4)
  }
  PHASE(0, 0, STAGE_A(7, 0, 1), )
  PHASE(0, 1, STAGE_A(7, 1, 1), )
  PHASE(0, 2, , )
  PHASE(0, 3, , VM0)
  PHASE(1, 0, , )
  PHASE(1, 1, , )
  PHASE(1, 2, , )
  PHASE(1, 3, , )

#pragma unroll
  for (int mf = 0; mf < 8; ++mf) {
#pragma unroll
    for (int nf = 0; nf < 4; ++nf) {
      const int col = bcol + wn * 64 + nf * 16 + c;
      const float bv = bias[col];
#pragma unroll
      for (int r = 0; r < 4; ++r) {
        const long grow = brow + wm * 128 + mf * 16 + g * 4 + r;
        const float v = acc[mf][nf][r] + bv;
        if (EPI == 0)
          ((uint16_t*)Cout)[grow * N + col] = f2b(v);
        else
          ((float*)Cout)[grow * N + col] = v;
      }
    }
  }
}

// ------- MFMA attention v5: multiplicative bf16 T-table (exp-fold) -------
__global__ __launch_bounds__(256, 4) void attn_mfma(
    const uint16_t* __restrict__ qkv,   // [100352][1536] bf16 (q|k|v)
    const float* __restrict__ logit_scale,
    const uint16_t* __restrict__ Tt,    // [w][h][nt][lane][mt][4] bf16
    uint16_t* __restrict__ outb) {      // [100352][512] bf16
  __shared__ uint16_t Vs[4][2048];      // per-wave V tile; reused for O repack
  const int tid = threadIdx.x;
  const int wave = tid >> 6, lane = tid & 63;
  const int g = lane >> 4, c = lane & 15;
  const int b = blockIdx.x >> 2;
  const int h = ((blockIdx.x & 3) << 2) | wave;
  const long rbase = (long)b * 49;

  uint16_t* vdst = Vs[wave];
#pragma unroll
  for (int i = 0; i < 4; ++i) {
    int chunk = i * 64 + lane;
    int row = chunk >> 2, part = chunk & 3;
    if (row > 48) { row = 0; part = 0; }
    GLOAD_LDS16(qkv + (rbase + row) * QKVN + 1024 + h * 32 + part * 8,
                vdst + i * 512 + lane * 8);
  }

  const long qoff = rbase * QKVN + h * 32;
  s16x8 kf[4], qf[4];
#pragma unroll
  for (int t = 0; t < 4; ++t) {
    int row = t * 16 + c;
    s16x8 kv = {}, qv = {};
    if (row < 49) {
      qv = *(const s16x8*)(qkv + qoff + (long)row * QKVN + g * 8);
      kv = *(const s16x8*)(qkv + qoff + (long)row * QKVN + 512 + g * 8);
    }
    float kfv[8], qfv[8];
    float kss = 0.f, qss = 0.f;
#pragma unroll
    for (int m = 0; m < 8; ++m) {
      kfv[m] = b2f((uint16_t)kv[m]); kss += kfv[m] * kfv[m];
      qfv[m] = b2f((uint16_t)qv[m]); qss += qfv[m] * qfv[m];
    }
    kss += __shfl_xor(kss, 16); kss += __shfl_xor(kss, 32);
    qss += __shfl_xor(qss, 16); qss += __shfl_xor(qss, 32);
    float kr = rsqrtf(fmaxf(kss, 1e-12f));
    float qr = rsqrtf(fmaxf(qss, 1e-12f));
#pragma unroll
    for (int m = 0; m < 8; ++m) {
      kv[m] = (short)f2b(kfv[m] * kr);
      qv[m] = (short)f2b(qfv[m] * qr);
    }
    kf[t] = kv; qf[t] = qv;
  }

  const float scale = __expf(fminf(logit_scale[h], 4.6051702f));
  const uint16_t* Tbase = Tt + (long)(((b & 63) * 16 + h)) * 4096;

  u32x4 aT[4][2];
  const int dstlo = (c + 16 * (g >> 1)) * 4;
  const int dsthi = (c + 16 * (2 + (g >> 1))) * 4;
  const bool godd = (g & 1) != 0;
  const bool low = (lane < 32);

#pragma unroll
  for (int nt = 0; nt < 4; ++nt) {
    s16x8 t01 = *(const s16x8*)(Tbase + nt * 1024 + lane * 16);
    s16x8 t23 = *(const s16x8*)(Tbase + nt * 1024 + lane * 16 + 8);

    f32x4 sv[4];
    __builtin_amdgcn_s_setprio(1);
#pragma unroll
    for (int mt = 0; mt < 4; ++mt)
      sv[mt] = __builtin_amdgcn_mfma_f32_16x16x32_bf16(
          kf[mt], qf[nt], f32x4{0.f, 0.f, 0.f, 0.f}, 0, 0, 0);
    __builtin_amdgcn_s_setprio(0);

    float mx = -3.0e38f;
#pragma unroll
    for (int mt = 0; mt < 4; ++mt)
#pragma unroll
      for (int j = 0; j < 4; ++j) {
        sv[mt][j] *= scale;
        mx = fmaxf(mx, sv[mt][j]);
      }
    mx = fmaxf(mx, __shfl_xor(mx, 16));
    mx = fmaxf(mx, __shfl_xor(mx, 32));
    float sum = 0.f;
#pragma unroll
    for (int mt = 0; mt < 4; ++mt) {
#pragma unroll
      for (int j = 0; j < 4; ++j) {
        uint16_t tb = (uint16_t)((mt < 2) ? t01[mt * 4 + j] : t23[(mt - 2) * 4 + j]);
        float e = b2f(tb) * __expf(sv[mt][j] - mx);
        sv[mt][j] = e; sum += e;
      }
    }
    sum += __shfl_xor(sum, 16);
    sum += __shfl_xor(sum, 32);
    float inv = 1.0f / sum;
#pragma unroll
    for (int mt = 0; mt < 4; ++mt)
#pragma unroll
      for (int j = 0; j < 4; ++j) sv[mt][j] *= inv;

    unsigned pk[4][2];
#pragma unroll
    for (int mt = 0; mt < 4; ++mt) {
      pk[mt][0] = (unsigned)f2b(sv[mt][0]) | ((unsigned)f2b(sv[mt][1]) << 16);
      pk[mt][1] = (unsigned)f2b(sv[mt][2]) | ((unsigned)f2b(sv[mt][3]) << 16);
    }
#pragma unroll
    for (int x = 0; x < 2; ++x)
#pragma unroll
      for (int K = 0; K < 2; ++K) {
        int vA = godd ? (int)pk[2 * K + 1][x] : (int)pk[2 * K][x];
        int dA = godd ? dsthi : dstlo;
        int rA = __builtin_amdgcn_ds_permute(dA, vA);
        int vB = godd ? (int)pk[2 * K][x] : (int)pk[2 * K + 1][x];
        int dB = godd ? dstlo : dsthi;
        int rB = __builtin_amdgcn_ds_permute(dB, vB);
        aT[nt][K][x]     = (unsigned)(low ? rA : rB);
        aT[nt][K][2 + x] = (unsigned)(low ? rB : rA);
      }
  }

  asm volatile("s_waitcnt vmcnt(0)" ::: "memory");

  f32x4 o[4][2];
#pragma unroll
  for (int qt = 0; qt < 4; ++qt)
#pragma unroll
    for (int dt = 0; dt < 2; ++dt) o[qt][dt] = f32x4{0.f, 0.f, 0.f, 0.f};

#pragma unroll
  for (int ks = 0; ks < 2; ++ks) {
    s16x8 vf[2];
#pragma unroll
    for (int dt = 0; dt < 2; ++dt) {
      int d = dt * 16 + c;
      s16x8 vv;
#pragma unroll
      for (int jj = 0; jj < 8; ++jj) {
        int k = ks * 32 + g * 8 + jj;
        vv[jj] = (short)vdst[k * 32 + d];
      }
      vf[dt] = vv;
    }
    __builtin_amdgcn_s_setprio(1);
#pragma unroll
    for (int qt = 0; qt < 4; ++qt) {
      s16x8 pf = __builtin_bit_cast(s16x8, aT[qt][ks]);
#pragma unroll
      for (int dt = 0; dt < 2; ++dt)
        o[qt][dt] = __builtin_amdgcn_mfma_f32_16x16x32_bf16(pf, vf[dt],
                                                            o[qt][dt], 0, 0, 0);
    }
    __builtin_amdgcn_s_setprio(0);
  }

#pragma unroll
  for (int qt = 0; qt < 4; ++qt) {
    int q0 = qt * 16 + g * 4;
#pragma unroll
    for (int dt = 0; dt < 2; ++dt)
#pragma unroll
      for (int j = 0; j < 4; ++j) {
        int q = q0 + j;
        if (q < 49) vdst[q * 40 + dt * 16 + c] = f2b(o[qt][dt][j]);
      }
  }
#pragma unroll
  for (int i = 0; i < 4; ++i) {
    int row = i * 16 + (lane >> 2);
    if (row < 49) {
      int chunk = lane & 3;
      s16x8 ov = *(const s16x8*)&vdst[row * 40 + chunk * 8];
      *(s16x8*)(outb + (rbase + row) * 512 + h * 32 + chunk * 8) = ov;
    }
  }
}

extern "C" void kernel_launch(void* const* d_in, const int* in_sizes, int n_in,
                              void* d_out, int out_size, void* d_ws,
                              size_t ws_size, hipStream_t stream) {
  const float* x = (const float*)d_in[0];
  const float* mask = (const float*)d_in[1];
  const float* qkv_w = (const float*)d_in[2];
  const float* q_bias = (const float*)d_in[3];
  const float* v_bias = (const float*)d_in[4];
  const float* logit_scale = (const float*)d_in[5];
  const float* rpe_w1 = (const float*)d_in[6];
  const float* rpe_b1 = (const float*)d_in[7];
  const float* rpe_w2 = (const float*)d_in[8];
  const float* proj_w = (const float*)d_in[9];
  const float* proj_b = (const float*)d_in[10];

  char* ws = (char*)d_ws;
  uint16_t* xb       = (uint16_t*)ws;                   // x bf16; later attn out
  uint16_t* qkvbuf   = (uint16_t*)(ws + 102760448L);    // [100352][1536]
  uint16_t* qkv_wT   = (uint16_t*)(ws + 411041792L);
  uint16_t* proj_wT  = (uint16_t*)(ws + 412614656L);
  float*    qkv_bias = (float*)(ws + 413138944L);
  float*    bias16   = (float*)(ws + 413145088L);
  uint16_t* Tt       = (uint16_t*)(ws + 413155904L);    // 8,388,608 B

  prep_all<<<53259, 256, 0, stream>>>(x, xb, qkv_w, proj_w, q_bias, v_bias,
                                      qkv_wT, proj_wT, qkv_bias, rpe_w1,
                                      rpe_b1, rpe_w2, bias16);
  build_T<<<1024, 256, 0, stream>>>(mask, bias16, Tt);

  gemm8p<0><<<2352, 512, 0, stream>>>(xb, qkv_wT, qkv_bias, qkvbuf, QKVN, 6);
  attn_mfma<<<8192, 256, 0, stream>>>(qkvbuf, logit_scale, Tt, xb);
  gemm8p<1><<<784, 512, 0, stream>>>(xb, proj_wT, proj_b, d_out, CDIM, 2);
}

// Round 15
// 496.716 us; speedup vs baseline: 1.0653x; 1.0075x over previous
//
#include <hip/hip_runtime.h>
#include <cstdint>

#define NTOK 49
#define CDIM 512
#define BW 2048
#define MROWS (BW * NTOK)   // 100352
#define QKVN 1536

typedef __attribute__((ext_vector_type(4))) float f32x4;
typedef __attribute__((ext_vector_type(8))) short s16x8;
typedef __attribute__((ext_vector_type(4))) unsigned int u32x4;

__device__ __forceinline__ uint16_t f2b(float f) {
  uint32_t u = __float_as_uint(f);
  u += 0x7fffu + ((u >> 16) & 1u);
  return (uint16_t)(u >> 16);
}
__device__ __forceinline__ float b2f(uint16_t h) {
  return __uint_as_float(((uint32_t)h) << 16);
}

#define GLOAD_LDS16(gp, lp)                                                    \
  __builtin_amdgcn_global_load_lds(                                            \
      (__attribute__((address_space(1))) void*)(gp),                           \
      (__attribute__((address_space(3))) void*)(lp), 16, 0, 0)

// ------- merged prep: x->bf16 | weight transpose+bf16 | rpe MLP table -------
__global__ __launch_bounds__(256) void prep_all(
    const float* __restrict__ x, uint16_t* __restrict__ xb,
    const float* __restrict__ qkv_w, const float* __restrict__ proj_w,
    const float* __restrict__ q_bias, const float* __restrict__ v_bias,
    uint16_t* __restrict__ qkv_wT, uint16_t* __restrict__ proj_wT,
    float* __restrict__ qkv_bias, const float* __restrict__ w1,
    const float* __restrict__ b1, const float* __restrict__ w2,
    float* __restrict__ bias16) {
  const int bid = blockIdx.x;
  if (bid < 50176) {
    long i = ((long)bid * 256 + threadIdx.x) * 4;
    f32x4 v = *(const f32x4*)(x + i);
    uint64_t p = (uint64_t)f2b(v[0]) | ((uint64_t)f2b(v[1]) << 16) |
                 ((uint64_t)f2b(v[2]) << 32) | ((uint64_t)f2b(v[3]) << 48);
    *(uint64_t*)(xb + i) = p;
  } else if (bid < 50176 + 3072) {
    int i = (bid - 50176) * 256 + threadIdx.x;
    if (i < QKVN * CDIM) {
      int nn = i / CDIM, kk = i % CDIM;
      qkv_wT[i] = f2b(qkv_w[(long)kk * QKVN + nn]);
    }
    if (i < CDIM * CDIM) {
      int nn = i / CDIM, kk = i % CDIM;
      proj_wT[i] = f2b(proj_w[(long)kk * CDIM + nn]);
    }
    if (i < QKVN) {
      float bv = (i < 512) ? q_bias[i] : (i < 1024 ? 0.f : v_bias[i - 1024]);
      qkv_bias[i] = bv;
    }
  } else {
    int i = (bid - 53248) * 256 + threadIdx.x;
    if (i >= 169 * 16) return;
    int f = i >> 4, h = i & 15;
    float d0 = (float)((f % 13) - 6);
    float d1 = (float)((f / 13) - 6);
    const float inv_log8 = 0.4808983469629878f;  // 1/ln(8)
    float v0 = (d0 / 11.0f) * (8.0f / 11.0f);
    float v1 = (d1 / 11.0f) * (8.0f / 11.0f);
    float f0 = copysignf(log1pf(fabsf(v0)) * inv_log8, v0);
    if (v0 == 0.f) f0 = 0.f;
    float f1 = copysignf(log1pf(fabsf(v1)) * inv_log8, v1);
    if (v1 == 0.f) f1 = 0.f;
    float acc = 0.f;
    for (int k = 0; k < 512; ++k) {
      float h1 = fmaxf(f0 * w1[k] + f1 * w1[512 + k] + b1[k], 0.f);
      acc += h1 * w2[k * 16 + h];
    }
    bias16[i] = 16.f / (1.f + expf(-acc));
  }
}

// ---- multiplicative table T = exp(mask + 16*sigmoid(pb)), bf16 ----
__global__ __launch_bounds__(256) void build_T(const float* __restrict__ mask,
                                               const float* __restrict__ bias16,
                                               uint16_t* __restrict__ Tt) {
  const int w = blockIdx.x >> 4, h = blockIdx.x & 15;
  const int nt = threadIdx.x >> 6, lane = threadIdx.x & 63;
  const int cc = lane & 15, gg = lane >> 4;
  const int q = nt * 16 + cc;
  uint16_t out[16];
#pragma unroll
  for (int mt = 0; mt < 4; ++mt)
#pragma unroll
    for (int j = 0; j < 4; ++j) {
      int k = mt * 16 + gg * 4 + j;
      float T;
      if (k >= 49) T = 0.f;
      else if (q >= 49) T = 1.f;
      else {
        int ridx = (q % 7 - k % 7 + 6) * 13 + (q / 7 - k / 7 + 6);
        T = __expf(mask[(long)w * 2401 + q * 49 + k] + bias16[ridx * 16 + h]);
      }
      out[mt * 4 + j] = f2b(T);
    }
  uint16_t* dst = Tt + ((long)(w * 16 + h) * 4096 + nt * 1024 + lane * 16);
#pragma unroll
  for (int p = 0; p < 2; ++p)
    *(u32x4*)(dst + p * 8) = *(const u32x4*)(out + p * 8);
}

// ============ 256x256 8-phase GEMM (round-4 proven form, FROZEN) ==========

#define STAGE_A(tile, half, buf)                                               \
  {                                                                            \
    const uint16_t* s_ = srcA + (half) * (128L * 512) + (long)(tile) * 64;     \
    uint16_t* d_ = &lds[(buf) * 32768 + (half) * 8192 + tid * 8];              \
    GLOAD_LDS16(s_, d_);                                                       \
    GLOAD_LDS16(s_ + 64 * 512, d_ + 4096);                                     \
  }

#define STAGE_B(tile, half, buf)                                               \
  {                                                                            \
    const uint16_t* s_ = srcB + (half) * (128L * 512) + (long)(tile) * 64;     \
    uint16_t* d_ = &lds[(buf) * 32768 + 16384 + (half) * 8192 + tid * 8];      \
    GLOAD_LDS16(s_, d_);                                                       \
    GLOAD_LDS16(s_ + 64 * 512, d_ + 4096);                                     \
  }

#define VM4 asm volatile("s_waitcnt vmcnt(4)" ::: "memory");
#define VM0 asm volatile("s_waitcnt vmcnt(0)" ::: "memory");

#define PHASE(buf, q, STAGES, TAIL)                                            \
  {                                                                            \
    s16x8 a00 = *(const s16x8*)&lds[(buf)*32768 + arow + (2*(q))*1024 + ax0];  \
    s16x8 a01 = *(const s16x8*)&lds[(buf)*32768 + arow + (2*(q))*1024 + ax1];  \
    s16x8 a10 = *(const s16x8*)&lds[(buf)*32768 + arow + (2*(q)+1)*1024 + ax0];\
    s16x8 a11 = *(const s16x8*)&lds[(buf)*32768 + arow + (2*(q)+1)*1024 + ax1];\
    if ((q) == 0) {                                                            \
      _Pragma("unroll")                                                        \
      for (int nf = 0; nf < 4; ++nf) {                                         \
        bfr0[nf] = *(const s16x8*)&lds[(buf)*32768 + brow_ + nf*1024 + ax0];   \
        bfr1[nf] = *(const s16x8*)&lds[(buf)*32768 + brow_ + nf*1024 + ax1];   \
      }                                                                        \
    }                                                                          \
    STAGES                                                                     \
    __builtin_amdgcn_s_barrier();                                              \
    asm volatile("s_waitcnt lgkmcnt(0)" ::: "memory");                         \
    __builtin_amdgcn_sched_barrier(0);                                         \
    __builtin_amdgcn_s_setprio(1);                                             \
    _Pragma("unroll")                                                          \
    for (int nf = 0; nf < 4; ++nf) {                                           \
      acc[2*(q)][nf] = __builtin_amdgcn_mfma_f32_16x16x32_bf16(                \
          a00, bfr0[nf], acc[2*(q)][nf], 0, 0, 0);                             \
      acc[2*(q)][nf] = __builtin_amdgcn_mfma_f32_16x16x32_bf16(                \
          a01, bfr1[nf], acc[2*(q)][nf], 0, 0, 0);                             \
      acc[2*(q)+1][nf] = __builtin_amdgcn_mfma_f32_16x16x32_bf16(              \
          a10, bfr0[nf], acc[2*(q)+1][nf], 0, 0, 0);                           \
      acc[2*(q)+1][nf] = __builtin_amdgcn_mfma_f32_16x16x32_bf16(              \
          a11, bfr1[nf], acc[2*(q)+1][nf], 0, 0, 0);                           \
    }                                                                          \
    __builtin_amdgcn_s_setprio(0);                                             \
    TAIL                                                                       \
    __builtin_amdgcn_s_barrier();                                              \
  }

template <int EPI>  // 0: bf16 out, 1: f32 out
__global__ __launch_bounds__(512, 2) void gemm8p(const uint16_t* __restrict__ A,
                                                 const uint16_t* __restrict__ BT,
                                                 const float* __restrict__ bias,
                                                 void* __restrict__ Cout,
                                                 int N, int ntn) {
  __shared__ uint16_t lds[2 * 32768];  // 131072 B
  const int tid = threadIdx.x;
  const int wave = tid >> 6, lane = tid & 63;
  const int wm = wave >> 2, wn = wave & 3;  // 2 x 4 waves
  const int c = lane & 15, g = lane >> 4;

  const int bid = blockIdx.x;
  const int nwg = gridDim.x;
  const int wg = (bid & 7) * (nwg >> 3) + (bid >> 3);  // XCD swizzle (nwg%8==0)
  const int mt = wg / ntn, nt = wg % ntn;
  const long brow = (long)mt * 256;
  const int bcol = nt * 256;

  const int lr0 = tid >> 3;
  const int chunk = tid & 7;
  const int scol = (chunk ^ (lr0 & 7)) * 8;
  const uint16_t* srcA = A + (brow + lr0) * 512 + scol;
  const uint16_t* srcB = BT + ((long)bcol + lr0) * 512 + scol;

  const int arow = wm * 8192 + c * 64;
  const int brow_ = 16384 + (wn >> 1) * 8192 + ((wn & 1) * 64 + c) * 64;
  const int ax0 = (g * 8) ^ ((c & 7) * 8);
  const int ax1 = (32 + g * 8) ^ ((c & 7) * 8);

  f32x4 acc[8][4];
#pragma unroll
  for (int i = 0; i < 8; ++i)
#pragma unroll
    for (int j = 0; j < 4; ++j) acc[i][j] = f32x4{0.f, 0.f, 0.f, 0.f};
  s16x8 bfr0[4], bfr1[4];

  STAGE_A(0, 0, 0); STAGE_A(0, 1, 0);
  STAGE_B(0, 0, 0); STAGE_B(0, 1, 0);
  STAGE_B(1, 0, 1); STAGE_B(1, 1, 1);
  VM4
  __builtin_amdgcn_s_barrier();

  for (int i = 0; i < 3; ++i) {
    const int t0 = 2 * i;
    PHASE(0, 0, STAGE_A(t0 + 1, 0, 1), )
    PHASE(0, 1, STAGE_A(t0 + 1, 1, 1), )
    PHASE(0, 2, STAGE_B(t0 + 2, 0, 0), )
    PHASE(0, 3, STAGE_B(t0 + 2, 1, 0), VM4)
    PHASE(1, 0, STAGE_A(t0 + 2, 0, 0), )
    PHASE(1, 1, STAGE_A(t0 + 2, 1, 0), )
    PHASE(1, 2, STAGE_B(t0 + 3, 0, 1), )
    PHASE(1, 3, STAGE_B(t0 + 3, 1, 1), VM4)
  }
  PHASE(0, 0, STAGE_A(7, 0, 1), )
  PHASE(0, 1, STAGE_A(7, 1, 1), )
  PHASE(0, 2, , )
  PHASE(0, 3, , VM0)
  PHASE(1, 0, , )
  PHASE(1, 1, , )
  PHASE(1, 2, , )
  PHASE(1, 3, , )

#pragma unroll
  for (int mf = 0; mf < 8; ++mf) {
#pragma unroll
    for (int nf = 0; nf < 4; ++nf) {
      const int col = bcol + wn * 64 + nf * 16 + c;
      const float bv = bias[col];
#pragma unroll
      for (int r = 0; r < 4; ++r) {
        const long grow = brow + wm * 128 + mf * 16 + g * 4 + r;
        const float v = acc[mf][nf][r] + bv;
        if (EPI == 0)
          ((uint16_t*)Cout)[grow * N + col] = f2b(v);
        else
          ((float*)Cout)[grow * N + col] = v;
      }
    }
  }
}

// --- MFMA attention v5b: T-table loads hoisted ahead of the nt loop ---
__global__ __launch_bounds__(256, 4) void attn_mfma(
    const uint16_t* __restrict__ qkv,   // [100352][1536] bf16 (q|k|v)
    const float* __restrict__ logit_scale,
    const uint16_t* __restrict__ Tt,    // [w][h][nt][lane][mt][4] bf16
    uint16_t* __restrict__ outb) {      // [100352][512] bf16
  __shared__ uint16_t Vs[4][2048];      // per-wave V tile; reused for O repack
  const int tid = threadIdx.x;
  const int wave = tid >> 6, lane = tid & 63;
  const int g = lane >> 4, c = lane & 15;
  const int b = blockIdx.x >> 2;
  const int h = ((blockIdx.x & 3) << 2) | wave;
  const long rbase = (long)b * 49;

  uint16_t* vdst = Vs[wave];
#pragma unroll
  for (int i = 0; i < 4; ++i) {
    int chunk = i * 64 + lane;
    int row = chunk >> 2, part = chunk & 3;
    if (row > 48) { row = 0; part = 0; }
    GLOAD_LDS16(qkv + (rbase + row) * QKVN + 1024 + h * 32 + part * 8,
                vdst + i * 512 + lane * 8);
  }

  // hoisted T-table loads for all 4 nt (latency hidden under Q/K norm + QK^T)
  const uint16_t* Tbase = Tt + (long)(((b & 63) * 16 + h)) * 4096;
  s16x8 tA[4], tB[4];
#pragma unroll
  for (int nt = 0; nt < 4; ++nt) {
    tA[nt] = *(const s16x8*)(Tbase + nt * 1024 + lane * 16);
    tB[nt] = *(const s16x8*)(Tbase + nt * 1024 + lane * 16 + 8);
  }

  const long qoff = rbase * QKVN + h * 32;
  s16x8 kf[4], qf[4];
#pragma unroll
  for (int t = 0; t < 4; ++t) {
    int row = t * 16 + c;
    s16x8 kv = {}, qv = {};
    if (row < 49) {
      qv = *(const s16x8*)(qkv + qoff + (long)row * QKVN + g * 8);
      kv = *(const s16x8*)(qkv + qoff + (long)row * QKVN + 512 + g * 8);
    }
    float kfv[8], qfv[8];
    float kss = 0.f, qss = 0.f;
#pragma unroll
    for (int m = 0; m < 8; ++m) {
      kfv[m] = b2f((uint16_t)kv[m]); kss += kfv[m] * kfv[m];
      qfv[m] = b2f((uint16_t)qv[m]); qss += qfv[m] * qfv[m];
    }
    kss += __shfl_xor(kss, 16); kss += __shfl_xor(kss, 32);
    qss += __shfl_xor(qss, 16); qss += __shfl_xor(qss, 32);
    float kr = rsqrtf(fmaxf(kss, 1e-12f));
    float qr = rsqrtf(fmaxf(qss, 1e-12f));
#pragma unroll
    for (int m = 0; m < 8; ++m) {
      kv[m] = (short)f2b(kfv[m] * kr);
      qv[m] = (short)f2b(qfv[m] * qr);
    }
    kf[t] = kv; qf[t] = qv;
  }

  const float scale = __expf(fminf(logit_scale[h], 4.6051702f));

  u32x4 aT[4][2];
  const int dstlo = (c + 16 * (g >> 1)) * 4;
  const int dsthi = (c + 16 * (2 + (g >> 1))) * 4;
  const bool godd = (g & 1) != 0;
  const bool low = (lane < 32);

#pragma unroll
  for (int nt = 0; nt < 4; ++nt) {
    f32x4 sv[4];
    __builtin_amdgcn_s_setprio(1);
#pragma unroll
    for (int mt = 0; mt < 4; ++mt)
      sv[mt] = __builtin_amdgcn_mfma_f32_16x16x32_bf16(
          kf[mt], qf[nt], f32x4{0.f, 0.f, 0.f, 0.f}, 0, 0, 0);
    __builtin_amdgcn_s_setprio(0);

    float mx = -3.0e38f;
#pragma unroll
    for (int mt = 0; mt < 4; ++mt)
#pragma unroll
      for (int j = 0; j < 4; ++j) {
        sv[mt][j] *= scale;
        mx = fmaxf(mx, sv[mt][j]);
      }
    mx = fmaxf(mx, __shfl_xor(mx, 16));
    mx = fmaxf(mx, __shfl_xor(mx, 32));
    float sum = 0.f;
#pragma unroll
    for (int mt = 0; mt < 4; ++mt) {
#pragma unroll
      for (int j = 0; j < 4; ++j) {
        uint16_t tb = (uint16_t)((mt < 2) ? tA[nt][mt * 4 + j]
                                          : tB[nt][(mt - 2) * 4 + j]);
        float e = b2f(tb) * __expf(sv[mt][j] - mx);
        sv[mt][j] = e; sum += e;
      }
    }
    sum += __shfl_xor(sum, 16);
    sum += __shfl_xor(sum, 32);
    float inv = 1.0f / sum;
#pragma unroll
    for (int mt = 0; mt < 4; ++mt)
#pragma unroll
      for (int j = 0; j < 4; ++j) sv[mt][j] *= inv;

    unsigned pk[4][2];
#pragma unroll
    for (int mt = 0; mt < 4; ++mt) {
      pk[mt][0] = (unsigned)f2b(sv[mt][0]) | ((unsigned)f2b(sv[mt][1]) << 16);
      pk[mt][1] = (unsigned)f2b(sv[mt][2]) | ((unsigned)f2b(sv[mt][3]) << 16);
    }
#pragma unroll
    for (int x = 0; x < 2; ++x)
#pragma unroll
      for (int K = 0; K < 2; ++K) {
        int vA = godd ? (int)pk[2 * K + 1][x] : (int)pk[2 * K][x];
        int dA = godd ? dsthi : dstlo;
        int rA = __builtin_amdgcn_ds_permute(dA, vA);
        int vB = godd ? (int)pk[2 * K][x] : (int)pk[2 * K + 1][x];
        int dB = godd ? dstlo : dsthi;
        int rB = __builtin_amdgcn_ds_permute(dB, vB);
        aT[nt][K][x]     = (unsigned)(low ? rA : rB);
        aT[nt][K][2 + x] = (unsigned)(low ? rB : rA);
      }
  }

  asm volatile("s_waitcnt vmcnt(0)" ::: "memory");

  f32x4 o[4][2];
#pragma unroll
  for (int qt = 0; qt < 4; ++qt)
#pragma unroll
    for (int dt = 0; dt < 2; ++dt) o[qt][dt] = f32x4{0.f, 0.f, 0.f, 0.f};

#pragma unroll
  for (int ks = 0; ks < 2; ++ks) {
    s16x8 vf[2];
#pragma unroll
    for (int dt = 0; dt < 2; ++dt) {
      int d = dt * 16 + c;
      s16x8 vv;
#pragma unroll
      for (int jj = 0; jj < 8; ++jj) {
        int k = ks * 32 + g * 8 + jj;
        vv[jj] = (short)vdst[k * 32 + d];
      }
      vf[dt] = vv;
    }
    __builtin_amdgcn_s_setprio(1);
#pragma unroll
    for (int qt = 0; qt < 4; ++qt) {
      s16x8 pf = __builtin_bit_cast(s16x8, aT[qt][ks]);
#pragma unroll
      for (int dt = 0; dt < 2; ++dt)
        o[qt][dt] = __builtin_amdgcn_mfma_f32_16x16x32_bf16(pf, vf[dt],
                                                            o[qt][dt], 0, 0, 0);
    }
    __builtin_amdgcn_s_setprio(0);
  }

#pragma unroll
  for (int qt = 0; qt < 4; ++qt) {
    int q0 = qt * 16 + g * 4;
#pragma unroll
    for (int dt = 0; dt < 2; ++dt)
#pragma unroll
      for (int j = 0; j < 4; ++j) {
        int q = q0 + j;
        if (q < 49) vdst[q * 40 + dt * 16 + c] = f2b(o[qt][dt][j]);
      }
  }
#pragma unroll
  for (int i = 0; i < 4; ++i) {
    int row = i * 16 + (lane >> 2);
    if (row < 49) {
      int chunk = lane & 3;
      s16x8 ov = *(const s16x8*)&vdst[row * 40 + chunk * 8];
      *(s16x8*)(outb + (rbase + row) * 512 + h * 32 + chunk * 8) = ov;
    }
  }
}

extern "C" void kernel_launch(void* const* d_in, const int* in_sizes, int n_in,
                              void* d_out, int out_size, void* d_ws,
                              size_t ws_size, hipStream_t stream) {
  const float* x = (const float*)d_in[0];
  const float* mask = (const float*)d_in[1];
  const float* qkv_w = (const float*)d_in[2];
  const float* q_bias = (const float*)d_in[3];
  const float* v_bias = (const float*)d_in[4];
  const float* logit_scale = (const float*)d_in[5];
  const float* rpe_w1 = (const float*)d_in[6];
  const float* rpe_b1 = (const float*)d_in[7];
  const float* rpe_w2 = (const float*)d_in[8];
  const float* proj_w = (const float*)d_in[9];
  const float* proj_b = (const float*)d_in[10];

  char* ws = (char*)d_ws;
  uint16_t* xb       = (uint16_t*)ws;                   // x bf16; later attn out
  uint16_t* qkvbuf   = (uint16_t*)(ws + 102760448L);    // [100352][1536]
  uint16_t* qkv_wT   = (uint16_t*)(ws + 411041792L);
  uint16_t* proj_wT  = (uint16_t*)(ws + 412614656L);
  float*    qkv_bias = (float*)(ws + 413138944L);
  float*    bias16   = (float*)(ws + 413145088L);
  uint16_t* Tt       = (uint16_t*)(ws + 413155904L);    // 8,388,608 B

  prep_all<<<53259, 256, 0, stream>>>(x, xb, qkv_w, proj_w, q_bias, v_bias,
                                      qkv_wT, proj_wT, qkv_bias, rpe_w1,
                                      rpe_b1, rpe_w2, bias16);
  build_T<<<1024, 256, 0, stream>>>(mask, bias16, Tt);

  gemm8p<0><<<2352, 512, 0, stream>>>(xb, qkv_wT, qkv_bias, qkvbuf, QKVN, 6);
  attn_mfma<<<8192, 256, 0, stream>>>(qkvbuf, logit_scale, Tt, xb);
  gemm8p<1><<<784, 512, 0, stream>>>(xb, proj_wT, proj_b, d_out, CDIM, 2);
}